// Round 1
// baseline (1712.855 us; speedup 1.0000x reference)
//
#include <hip/hip_runtime.h>
#include <math.h>

// Problem constants: N=8192, DIM=64, K=32, ALPHA=1.0
// d_in order: node_emb[8192*64], noise[8192*8192], W1[64*64], b1[64], W2[64*64], b2[64]
// out: 8192*8192 fp32

// ---------------------------------------------------------------------------
// Kernel 1: VV[i][2k] = v1[i][k], VV[i][2k+1] = v2[i][k]
// v = gelu(emb @ W.T + b), exact-erf gelu. In-order fmaf over k (BLAS-like).
// ---------------------------------------------------------------------------
__global__ __launch_bounds__(256) void compute_vv(
    const float* __restrict__ emb, const float* __restrict__ W1,
    const float* __restrict__ b1, const float* __restrict__ W2,
    const float* __restrict__ b2, float* __restrict__ VV)
{
    __shared__ float sW[2][64 * 65];   // +1 dword row pad: banks (o+k)%32, conflict-free
    __shared__ float sb[2][64];
    __shared__ float semb[2][64];
    int tid = threadIdx.x;
    for (int t = tid; t < 64 * 64; t += 256) {
        int o = t >> 6, k = t & 63;
        sW[0][o * 65 + k] = W1[t];
        sW[1][o * 65 + k] = W2[t];
    }
    if (tid < 64) { sb[0][tid] = b1[tid]; sb[1][tid] = b2[tid]; }
    int i0 = blockIdx.x * 2;
    if (tid < 128) semb[tid >> 6][tid & 63] = emb[(size_t)i0 * 64 + tid];
    __syncthreads();

    int li = tid >> 7;        // local row 0..1
    int c  = tid & 127;       // 0..127 : c = 2*o + w
    int o  = c >> 1;
    int w  = c & 1;
    const float* wr = &sW[w][o * 65];
    const float* e  = &semb[li][0];
    float acc = 0.0f;
#pragma unroll
    for (int k = 0; k < 64; ++k) acc = fmaf(e[k], wr[k], acc);
    float x = acc + sb[w][o];                 // ALPHA==1.0 exact no-op, skipped
    double xd = (double)x;
    double g = 0.5 * xd * (1.0 + erf(xd * 0.70710678118654752440));
    VV[(size_t)(i0 + li) * 128 + c] = (float)g;
}

// ---------------------------------------------------------------------------
// Kernel 2: adj = relu(v1 v2^T - v2 v1^T) -> written to d_out (clears poison).
// 128x128 tile per block, 8x8 per thread (two separated 4-col quads so LDS
// column reads are 2-way-max bank aliased = free). k staged in two halves of
// 32, de-interleaved k-major in LDS. In-order fmaf over k=0..63, single
// accumulator per entry -> mirrors BLAS sgemm accumulation exactly.
// ---------------------------------------------------------------------------
__global__ __launch_bounds__(256, 2) void adj_gemm(
    const float* __restrict__ VV, float* __restrict__ out)
{
    __shared__ __align__(16) float Ar1[32][132];   // rows, v1, k-major (132: pad, keeps 16B align)
    __shared__ __align__(16) float Ar2[32][132];   // rows, v2
    __shared__ __align__(16) float Ac1[32][132];   // cols, v1
    __shared__ __align__(16) float Ac2[32][132];   // cols, v2
    int tid  = threadIdx.x;
    int bi   = blockIdx.x, bj = blockIdx.y;
    int trow = tid >> 4, tcol = tid & 15;
    const int grow = bi * 128, gcol = bj * 128;

    float d1[8][8], d2[8][8];
#pragma unroll
    for (int r = 0; r < 8; ++r)
#pragma unroll
        for (int c = 0; c < 8; ++c) { d1[r][c] = 0.0f; d2[r][c] = 0.0f; }

    const float4* VV4 = (const float4*)VV;
    for (int kb = 0; kb < 2; ++kb) {
        __syncthreads();
        // stage 128 rows + 128 cols, half-k each (8 float4 pairs per thread)
        for (int g = tid; g < 2048; g += 256) {
            int row = g >> 4, off = g & 15;
            float4 f = VV4[(size_t)(grow + row) * 32 + kb * 16 + off];
            float4 h = VV4[(size_t)(gcol + row) * 32 + kb * 16 + off];
            int kk = off * 2;
            Ar1[kk][row] = f.x; Ar2[kk][row] = f.y;
            Ar1[kk + 1][row] = f.z; Ar2[kk + 1][row] = f.w;
            Ac1[kk][row] = h.x; Ac2[kk][row] = h.y;
            Ac1[kk + 1][row] = h.z; Ac2[kk + 1][row] = h.w;
        }
        __syncthreads();
#pragma unroll 2
        for (int k = 0; k < 32; ++k) {
            float rv1[8], rv2[8], cv1[8], cv2[8];
            *(float4*)&rv1[0] = *(const float4*)&Ar1[k][trow * 4];
            *(float4*)&rv1[4] = *(const float4*)&Ar1[k][64 + trow * 4];
            *(float4*)&rv2[0] = *(const float4*)&Ar2[k][trow * 4];
            *(float4*)&rv2[4] = *(const float4*)&Ar2[k][64 + trow * 4];
            *(float4*)&cv1[0] = *(const float4*)&Ac1[k][tcol * 4];
            *(float4*)&cv1[4] = *(const float4*)&Ac1[k][64 + tcol * 4];
            *(float4*)&cv2[0] = *(const float4*)&Ac2[k][tcol * 4];
            *(float4*)&cv2[4] = *(const float4*)&Ac2[k][64 + tcol * 4];
#pragma unroll
            for (int r = 0; r < 8; ++r)
#pragma unroll
                for (int c = 0; c < 8; ++c) {
                    d1[r][c] = fmaf(rv1[r], cv2[c], d1[r][c]);
                    d2[r][c] = fmaf(rv2[r], cv1[c], d2[r][c]);
                }
        }
    }
    // epilogue: adj = relu(d1 - d2), coalesced float4 stores
#pragma unroll
    for (int rr = 0; rr < 8; ++rr) {
        int r = (rr < 4) ? (trow * 4 + rr) : (64 + trow * 4 + (rr - 4));
        float4 o0, o1;
        o0.x = fmaxf(d1[rr][0] - d2[rr][0], 0.0f);
        o0.y = fmaxf(d1[rr][1] - d2[rr][1], 0.0f);
        o0.z = fmaxf(d1[rr][2] - d2[rr][2], 0.0f);
        o0.w = fmaxf(d1[rr][3] - d2[rr][3], 0.0f);
        o1.x = fmaxf(d1[rr][4] - d2[rr][4], 0.0f);
        o1.y = fmaxf(d1[rr][5] - d2[rr][5], 0.0f);
        o1.z = fmaxf(d1[rr][6] - d2[rr][6], 0.0f);
        o1.w = fmaxf(d1[rr][7] - d2[rr][7], 0.0f);
        float* op = out + (size_t)(grow + r) * 8192 + gcol;
        *(float4*)(op + tcol * 4)      = o0;
        *(float4*)(op + 64 + tcol * 4) = o1;
    }
}

// ---------------------------------------------------------------------------
// Kernel 3: per-row top-32 of (adj + noise*0.01), then rewrite row in place:
// zeros everywhere except the 32 selected positions (exact adj values).
// Iterative argmax with per-thread cached max: only the winner's owner
// rescans. Tie-break: smallest index (matches lax.top_k).
// ---------------------------------------------------------------------------
__global__ __launch_bounds__(256) void topk_rewrite(
    const float* __restrict__ noise, float* __restrict__ out)
{
    __shared__ __align__(16) float sc[8192];
    __shared__ unsigned int flags[256];
    __shared__ float rb[4];
    __shared__ int ri[4];
    __shared__ int winner;
    int tid = threadIdx.x;
    int row = blockIdx.x;
    float* orow = out + (size_t)row * 8192;
    const float* nrow = noise + (size_t)row * 8192;
    const float4* o4 = (const float4*)orow;
    const float4* n4 = (const float4*)nrow;

    flags[tid] = 0u;
    for (int t = tid; t < 2048; t += 256) {
        float4 a  = o4[t];
        float4 nz = n4[t];
        float4 s;
        // exactly (adj + (noise*0.01f)): block FMA contraction
        s.x = __fadd_rn(a.x, __fmul_rn(nz.x, 0.01f));
        s.y = __fadd_rn(a.y, __fmul_rn(nz.y, 0.01f));
        s.z = __fadd_rn(a.z, __fmul_rn(nz.z, 0.01f));
        s.w = __fadd_rn(a.w, __fmul_rn(nz.w, 0.01f));
        ((float4*)sc)[t] = s;
    }
    __syncthreads();

    float myB = -INFINITY; int myI = 0x7fffffff;
    for (int t = tid; t < 8192; t += 256) {
        float v = sc[t];
        if (v > myB) { myB = v; myI = t; }
    }

    for (int it = 0; it < 32; ++it) {
        float b = myB; int bx = myI;
#pragma unroll
        for (int off = 32; off > 0; off >>= 1) {
            float ob = __shfl_down(b, off);
            int   oi = __shfl_down(bx, off);
            if (ob > b || (ob == b && oi < bx)) { b = ob; bx = oi; }
        }
        if ((tid & 63) == 0) { rb[tid >> 6] = b; ri[tid >> 6] = bx; }
        __syncthreads();
        if (tid == 0) {
            float fb = rb[0]; int fi = ri[0];
            for (int w2 = 1; w2 < 4; ++w2)
                if (rb[w2] > fb || (rb[w2] == fb && ri[w2] < fi)) { fb = rb[w2]; fi = ri[w2]; }
            flags[fi >> 5] |= (1u << (fi & 31));
            winner = fi;
        }
        __syncthreads();
        int wi = winner;
        if ((wi & 255) == tid) {
            myB = -INFINITY; myI = 0x7fffffff;
            for (int t = tid; t < 8192; t += 256) {
                if ((flags[t >> 5] >> (t & 31)) & 1u) continue;
                float v = sc[t];
                if (v > myB) { myB = v; myI = t; }
            }
        }
    }
    __syncthreads();

    for (int t = tid; t < 2048; t += 256) {
        float4 a = o4[t];
        int j = t * 4;
        unsigned int fw = flags[j >> 5];   // j%4==0 -> all 4 bits in same word
        float4 o;
        o.x = ((fw >> ((j + 0) & 31)) & 1u) ? a.x : 0.0f;
        o.y = ((fw >> ((j + 1) & 31)) & 1u) ? a.y : 0.0f;
        o.z = ((fw >> ((j + 2) & 31)) & 1u) ? a.z : 0.0f;
        o.w = ((fw >> ((j + 3) & 31)) & 1u) ? a.w : 0.0f;
        ((float4*)orow)[t] = o;
    }
}

// ---------------------------------------------------------------------------
extern "C" void kernel_launch(void* const* d_in, const int* in_sizes, int n_in,
                              void* d_out, int out_size, void* d_ws, size_t ws_size,
                              hipStream_t stream) {
    (void)in_sizes; (void)n_in; (void)out_size; (void)ws_size;
    const float* emb   = (const float*)d_in[0];
    const float* noise = (const float*)d_in[1];
    const float* W1    = (const float*)d_in[2];
    const float* b1    = (const float*)d_in[3];
    const float* W2    = (const float*)d_in[4];
    const float* b2    = (const float*)d_in[5];
    float* out = (float*)d_out;
    float* VV  = (float*)d_ws;   // 8192*128 floats = 4 MiB scratch

    hipLaunchKernelGGL(compute_vv, dim3(4096), dim3(256), 0, stream,
                       emb, W1, b1, W2, b2, VV);
    hipLaunchKernelGGL(adj_gemm, dim3(64, 64), dim3(256), 0, stream, VV, out);
    hipLaunchKernelGGL(topk_rewrite, dim3(8192), dim3(256), 0, stream, noise, out);
}

// Round 2
// 822.870 us; speedup vs baseline: 2.0816x; 2.0816x over previous
//
#include <hip/hip_runtime.h>
#include <math.h>

// Problem constants: N=8192, DIM=64, K=32, ALPHA=1.0
// d_in order: node_emb[8192*64], noise[8192*8192], W1[64*64], b1[64], W2[64*64], b2[64]
// out: 8192*8192 fp32

// ---------------------------------------------------------------------------
// Kernel 1: VV[i][2k] = v1[i][k], VV[i][2k+1] = v2[i][k]
// v = gelu(emb @ W.T + b), exact-erf gelu. In-order fmaf over k (BLAS-like).
// ---------------------------------------------------------------------------
__global__ __launch_bounds__(256) void compute_vv(
    const float* __restrict__ emb, const float* __restrict__ W1,
    const float* __restrict__ b1, const float* __restrict__ W2,
    const float* __restrict__ b2, float* __restrict__ VV)
{
    __shared__ float sW[2][64 * 65];   // +1 dword row pad: banks (o+k)%32, conflict-free
    __shared__ float sb[2][64];
    __shared__ float semb[2][64];
    int tid = threadIdx.x;
    for (int t = tid; t < 64 * 64; t += 256) {
        int o = t >> 6, k = t & 63;
        sW[0][o * 65 + k] = W1[t];
        sW[1][o * 65 + k] = W2[t];
    }
    if (tid < 64) { sb[0][tid] = b1[tid]; sb[1][tid] = b2[tid]; }
    int i0 = blockIdx.x * 2;
    if (tid < 128) semb[tid >> 6][tid & 63] = emb[(size_t)i0 * 64 + tid];
    __syncthreads();

    int li = tid >> 7;        // local row 0..1
    int c  = tid & 127;       // 0..127 : c = 2*o + w
    int o  = c >> 1;
    int w  = c & 1;
    const float* wr = &sW[w][o * 65];
    const float* e  = &semb[li][0];
    float acc = 0.0f;
#pragma unroll
    for (int k = 0; k < 64; ++k) acc = fmaf(e[k], wr[k], acc);
    float x = acc + sb[w][o];                 // ALPHA==1.0 exact no-op, skipped
    double xd = (double)x;
    double g = 0.5 * xd * (1.0 + erf(xd * 0.70710678118654752440));
    VV[(size_t)(i0 + li) * 128 + c] = (float)g;
}

// ---------------------------------------------------------------------------
// Kernel 2: adj = relu(v1 v2^T - v2 v1^T) -> written to d_out (clears poison).
// 128x128 tile per block, 8x8 per thread (two separated 4-col quads so LDS
// column reads are 2-way-max bank aliased = free). k staged in two halves of
// 32, de-interleaved k-major in LDS. In-order fmaf over k=0..63, single
// accumulator per entry -> mirrors BLAS sgemm accumulation exactly.
// ---------------------------------------------------------------------------
__global__ __launch_bounds__(256, 2) void adj_gemm(
    const float* __restrict__ VV, float* __restrict__ out)
{
    __shared__ __align__(16) float Ar1[32][132];   // rows, v1, k-major (132: pad, keeps 16B align)
    __shared__ __align__(16) float Ar2[32][132];   // rows, v2
    __shared__ __align__(16) float Ac1[32][132];   // cols, v1
    __shared__ __align__(16) float Ac2[32][132];   // cols, v2
    int tid  = threadIdx.x;
    int bi   = blockIdx.x, bj = blockIdx.y;
    int trow = tid >> 4, tcol = tid & 15;
    const int grow = bi * 128, gcol = bj * 128;

    float d1[8][8], d2[8][8];
#pragma unroll
    for (int r = 0; r < 8; ++r)
#pragma unroll
        for (int c = 0; c < 8; ++c) { d1[r][c] = 0.0f; d2[r][c] = 0.0f; }

    const float4* VV4 = (const float4*)VV;
    for (int kb = 0; kb < 2; ++kb) {
        __syncthreads();
        // stage 128 rows + 128 cols, half-k each (8 float4 pairs per thread)
        for (int g = tid; g < 2048; g += 256) {
            int row = g >> 4, off = g & 15;
            float4 f = VV4[(size_t)(grow + row) * 32 + kb * 16 + off];
            float4 h = VV4[(size_t)(gcol + row) * 32 + kb * 16 + off];
            int kk = off * 2;
            Ar1[kk][row] = f.x; Ar2[kk][row] = f.y;
            Ar1[kk + 1][row] = f.z; Ar2[kk + 1][row] = f.w;
            Ac1[kk][row] = h.x; Ac2[kk][row] = h.y;
            Ac1[kk + 1][row] = h.z; Ac2[kk + 1][row] = h.w;
        }
        __syncthreads();
#pragma unroll 2
        for (int k = 0; k < 32; ++k) {
            float rv1[8], rv2[8], cv1[8], cv2[8];
            *(float4*)&rv1[0] = *(const float4*)&Ar1[k][trow * 4];
            *(float4*)&rv1[4] = *(const float4*)&Ar1[k][64 + trow * 4];
            *(float4*)&rv2[0] = *(const float4*)&Ar2[k][trow * 4];
            *(float4*)&rv2[4] = *(const float4*)&Ar2[k][64 + trow * 4];
            *(float4*)&cv1[0] = *(const float4*)&Ac1[k][tcol * 4];
            *(float4*)&cv1[4] = *(const float4*)&Ac1[k][64 + tcol * 4];
            *(float4*)&cv2[0] = *(const float4*)&Ac2[k][tcol * 4];
            *(float4*)&cv2[4] = *(const float4*)&Ac2[k][64 + tcol * 4];
#pragma unroll
            for (int r = 0; r < 8; ++r)
#pragma unroll
                for (int c = 0; c < 8; ++c) {
                    d1[r][c] = fmaf(rv1[r], cv2[c], d1[r][c]);
                    d2[r][c] = fmaf(rv2[r], cv1[c], d2[r][c]);
                }
        }
    }
    // epilogue: adj = relu(d1 - d2), coalesced float4 stores
#pragma unroll
    for (int rr = 0; rr < 8; ++rr) {
        int r = (rr < 4) ? (trow * 4 + rr) : (64 + trow * 4 + (rr - 4));
        float4 o0, o1;
        o0.x = fmaxf(d1[rr][0] - d2[rr][0], 0.0f);
        o0.y = fmaxf(d1[rr][1] - d2[rr][1], 0.0f);
        o0.z = fmaxf(d1[rr][2] - d2[rr][2], 0.0f);
        o0.w = fmaxf(d1[rr][3] - d2[rr][3], 0.0f);
        o1.x = fmaxf(d1[rr][4] - d2[rr][4], 0.0f);
        o1.y = fmaxf(d1[rr][5] - d2[rr][5], 0.0f);
        o1.z = fmaxf(d1[rr][6] - d2[rr][6], 0.0f);
        o1.w = fmaxf(d1[rr][7] - d2[rr][7], 0.0f);
        float* op = out + (size_t)(grow + r) * 8192 + gcol;
        *(float4*)(op + tcol * 4)      = o0;
        *(float4*)(op + 64 + tcol * 4) = o1;
    }
}

// ---------------------------------------------------------------------------
// Kernel 3 (radix select): per-row top-32 of (adj + noise*0.01).
// Order-preserving uint keys in LDS; 3-pass histogram radix select finds the
// exact 32-bit threshold key T and the tie-count r; mark key>T plus the r
// smallest-index keys ==T (bit-exact lax.top_k tie-break). Then rewrite row:
// zeros + the 32 winner adj values (re-read as scattered dwords, L2-warm).
// No serial per-element loops; ~8 barriers per row total.
// ---------------------------------------------------------------------------
__device__ __forceinline__ unsigned fkey(float f) {
    unsigned u = __float_as_uint(f);
    return (u & 0x80000000u) ? ~u : (u | 0x80000000u);
}

// Pick the bin where the top-'krem' boundary falls. hist[nb], nb in {1024,2048}.
// Writes *sh_bin = chosen bin, *sh_above = #elements in strictly higher bins.
__device__ __forceinline__ void select_bin(
    unsigned* __restrict__ hist, unsigned* __restrict__ chs,
    int nb, int tid, int krem, int* __restrict__ sh_bin, int* __restrict__ sh_above)
{
    int bpt  = nb >> 8;          // bins per thread (8 or 4)
    int base = tid * bpt;
    unsigned s = 0;
    for (int i = 0; i < bpt; ++i) s += hist[base + i];
    chs[tid] = s;
    __syncthreads();
    unsigned v = s;              // inclusive suffix sum over chunks
    for (int off = 1; off < 256; off <<= 1) {
        unsigned add = (tid + off < 256) ? chs[tid + off] : 0u;
        __syncthreads();
        v += add; chs[tid] = v;
        __syncthreads();
    }
    unsigned above = v - s;      // elements in chunks strictly after mine
    if (above < (unsigned)krem && above + s >= (unsigned)krem) {  // unique thread
        unsigned cum = above;
        for (int i = bpt - 1; i >= 0; --i) {
            unsigned c = hist[base + i];
            if (cum + c >= (unsigned)krem) { *sh_bin = base + i; *sh_above = (int)cum; break; }
            cum += c;
        }
    }
    __syncthreads();
}

__global__ __launch_bounds__(256) void topk_radix(
    const float* __restrict__ noise, float* __restrict__ out)
{
    __shared__ __align__(16) unsigned keys[8192];   // 32 KB
    __shared__ unsigned hist[2048];                 // 8 KB
    __shared__ unsigned chs[256];
    __shared__ unsigned flags[256];                 // 8192-bit selection mask
    __shared__ int      eqidx[64];
    __shared__ int      winlist[32];
    __shared__ float    wval[32];
    __shared__ int      sh_bin, sh_above, sh_eqcnt, sh_wcnt;

    int tid = threadIdx.x;
    int row = blockIdx.x;
    float*       orow = out   + (size_t)row * 8192;
    const float* nrow = noise + (size_t)row * 8192;
    const float4* o4 = (const float4*)orow;
    const float4* n4 = (const float4*)nrow;

    for (int i = tid; i < 2048; i += 256) hist[i] = 0u;
    flags[tid] = 0u;
    if (tid == 0) { sh_eqcnt = 0; sh_wcnt = 0; }

    // Load row, compute scores exactly as ref (block FMA contraction), build
    // keys, and do pass-0 histogram (bits [31:21]) in the same sweep.
    for (int t = tid; t < 2048; t += 256) {
        float4 a  = o4[t];
        float4 nz = n4[t];
        unsigned k0 = fkey(__fadd_rn(a.x, __fmul_rn(nz.x, 0.01f)));
        unsigned k1 = fkey(__fadd_rn(a.y, __fmul_rn(nz.y, 0.01f)));
        unsigned k2 = fkey(__fadd_rn(a.z, __fmul_rn(nz.z, 0.01f)));
        unsigned k3 = fkey(__fadd_rn(a.w, __fmul_rn(nz.w, 0.01f)));
        ((uint4*)keys)[t] = make_uint4(k0, k1, k2, k3);
        atomicAdd(&hist[k0 >> 21], 1u);
        atomicAdd(&hist[k1 >> 21], 1u);
        atomicAdd(&hist[k2 >> 21], 1u);
        atomicAdd(&hist[k3 >> 21], 1u);
    }
    __syncthreads();

    // Pass 0: bits [31:21]
    int krem = 32;
    select_bin(hist, chs, 2048, tid, krem, &sh_bin, &sh_above);
    unsigned pref0 = (unsigned)sh_bin;
    krem -= sh_above;

    // Pass 1: bits [20:10] within pref0
    __syncthreads();
    for (int i = tid; i < 2048; i += 256) hist[i] = 0u;
    __syncthreads();
    for (int t = tid; t < 8192; t += 256) {
        unsigned k = keys[t];
        if ((k >> 21) == pref0) atomicAdd(&hist[(k >> 10) & 0x7FFu], 1u);
    }
    __syncthreads();
    select_bin(hist, chs, 2048, tid, krem, &sh_bin, &sh_above);
    unsigned pref01 = (pref0 << 11) | (unsigned)sh_bin;
    krem -= sh_above;

    // Pass 2: bits [9:0] within pref01
    __syncthreads();
    for (int i = tid; i < 1024; i += 256) hist[i] = 0u;
    __syncthreads();
    for (int t = tid; t < 8192; t += 256) {
        unsigned k = keys[t];
        if ((k >> 10) == pref01) atomicAdd(&hist[k & 0x3FFu], 1u);
    }
    __syncthreads();
    select_bin(hist, chs, 1024, tid, krem, &sh_bin, &sh_above);
    unsigned T = (pref01 << 10) | (unsigned)sh_bin;
    krem -= sh_above;
    int r = krem;                       // take r smallest-index elements ==T

    // Mark selection: key > T always in; gather ==T candidates.
    for (int t = tid; t < 8192; t += 256) {
        unsigned k = keys[t];
        if (k > T) {
            atomicOr(&flags[t >> 5], 1u << (t & 31));
        } else if (k == T) {
            int p = atomicAdd(&sh_eqcnt, 1);
            if (p < 64) eqidx[p] = t;
        }
    }
    __syncthreads();
    int eqc = sh_eqcnt;
    if (eqc <= 64) {
        if (tid < eqc) {
            int my = eqidx[tid];
            int rank = 0;
            for (int j = 0; j < eqc; ++j) rank += (eqidx[j] < my) ? 1 : 0;
            if (rank < r) atomicOr(&flags[my >> 5], 1u << (my & 31));
        }
    } else {
        // pathological mass-tie fallback (still exact)
        if (tid == 0) {
            int taken = 0;
            for (int t = 0; t < 8192 && taken < r; ++t)
                if (keys[t] == T) { flags[t >> 5] |= 1u << (t & 31); ++taken; }
        }
    }
    __syncthreads();

    // Gather the exactly-32 winners, fetch their adj values (pre-overwrite).
    for (int t = tid; t < 8192; t += 256) {
        if ((flags[t >> 5] >> (t & 31)) & 1u) {
            int p = atomicAdd(&sh_wcnt, 1);
            winlist[p] = t;
        }
    }
    __syncthreads();
    if (tid < 32) wval[tid] = orow[winlist[tid]];
    __syncthreads();
    // Zero the row, then scatter the 32 winner values.
    float4 z = make_float4(0.0f, 0.0f, 0.0f, 0.0f);
    for (int t = tid; t < 2048; t += 256) ((float4*)orow)[t] = z;
    __syncthreads();
    if (tid < 32) orow[winlist[tid]] = wval[tid];
}

// ---------------------------------------------------------------------------
extern "C" void kernel_launch(void* const* d_in, const int* in_sizes, int n_in,
                              void* d_out, int out_size, void* d_ws, size_t ws_size,
                              hipStream_t stream) {
    (void)in_sizes; (void)n_in; (void)out_size; (void)ws_size;
    const float* emb   = (const float*)d_in[0];
    const float* noise = (const float*)d_in[1];
    const float* W1    = (const float*)d_in[2];
    const float* b1    = (const float*)d_in[3];
    const float* W2    = (const float*)d_in[4];
    const float* b2    = (const float*)d_in[5];
    float* out = (float*)d_out;
    float* VV  = (float*)d_ws;   // 8192*128 floats = 4 MiB scratch

    hipLaunchKernelGGL(compute_vv, dim3(4096), dim3(256), 0, stream,
                       emb, W1, b1, W2, b2, VV);
    hipLaunchKernelGGL(adj_gemm, dim3(64, 64), dim3(256), 0, stream, VV, out);
    hipLaunchKernelGGL(topk_radix, dim3(8192), dim3(256), 0, stream, noise, out);
}

// Round 4
// 673.354 us; speedup vs baseline: 2.5438x; 1.2220x over previous
//
#include <hip/hip_runtime.h>
#include <math.h>

// Problem constants: N=8192, DIM=64, K=32, ALPHA=1.0
// d_in order: node_emb[8192*64], noise[8192*8192], W1[64*64], b1[64], W2[64*64], b2[64]
// out: 8192*8192 fp32

// ---------------------------------------------------------------------------
// Kernel 1: VV[i][2k] = v1[i][k], VV[i][2k+1] = v2[i][k]
// v = gelu(emb @ W.T + b), exact-erf gelu. In-order fmaf over k (BLAS-like).
// ---------------------------------------------------------------------------
__global__ __launch_bounds__(256) void compute_vv(
    const float* __restrict__ emb, const float* __restrict__ W1,
    const float* __restrict__ b1, const float* __restrict__ W2,
    const float* __restrict__ b2, float* __restrict__ VV)
{
    __shared__ float sW[2][64 * 65];
    __shared__ float sb[2][64];
    __shared__ float semb[2][64];
    int tid = threadIdx.x;
    for (int t = tid; t < 64 * 64; t += 256) {
        int o = t >> 6, k = t & 63;
        sW[0][o * 65 + k] = W1[t];
        sW[1][o * 65 + k] = W2[t];
    }
    if (tid < 64) { sb[0][tid] = b1[tid]; sb[1][tid] = b2[tid]; }
    int i0 = blockIdx.x * 2;
    if (tid < 128) semb[tid >> 6][tid & 63] = emb[(size_t)i0 * 64 + tid];
    __syncthreads();

    int li = tid >> 7;
    int c  = tid & 127;
    int o  = c >> 1;
    int w  = c & 1;
    const float* wr = &sW[w][o * 65];
    const float* e  = &semb[li][0];
    float acc = 0.0f;
#pragma unroll
    for (int k = 0; k < 64; ++k) acc = fmaf(e[k], wr[k], acc);
    float x = acc + sb[w][o];
    double xd = (double)x;
    double g = 0.5 * xd * (1.0 + erf(xd * 0.70710678118654752440));
    VV[(size_t)(i0 + li) * 128 + c] = (float)g;
}

// ---------------------------------------------------------------------------
// Kernel 2: adj = relu(v1 v2^T - v2 v1^T), antisymmetric-exploiting version.
// M[j][i] == -M[i][j] BIT-EXACTLY (fmaf(a,b,c)==fmaf(b,a,c), same k order),
// so only upper-triangular tiles (bi<=bj) are computed; the mirror tile is
// relu(d2-d1) transposed through LDS (reusing the staging buffer). Diagonal
// tiles are written twice with identical values (benign).
// R3 BUGFIX: mirror writeback now covers all 32 float4/row (was 16 -> half
// of every lower-triangle tile left unwritten).
// ---------------------------------------------------------------------------
__global__ __launch_bounds__(256, 2) void adj_gemm_tri(
    const float* __restrict__ VV, float* __restrict__ out)
{
    int bi = blockIdx.x, bj = blockIdx.y;
    if (bj < bi) return;                 // lower triangle: mirrored by (bj,bi)

    __shared__ __align__(16) float smem[16896];   // 66 KB, dual-purpose
    float* Ar1 = smem;                   // [32][132] rows v1, k-major
    float* Ar2 = smem + 4224;            // [32][132] rows v2
    float* Ac1 = smem + 8448;            // [32][132] cols v1
    float* Ac2 = smem + 12672;           // [32][132] cols v2

    int tid  = threadIdx.x;
    int trow = tid >> 4, tcol = tid & 15;
    const int grow = bi * 128, gcol = bj * 128;

    float d1[8][8], d2[8][8];
#pragma unroll
    for (int r = 0; r < 8; ++r)
#pragma unroll
        for (int c = 0; c < 8; ++c) { d1[r][c] = 0.0f; d2[r][c] = 0.0f; }

    const float4* VV4 = (const float4*)VV;
    for (int kb = 0; kb < 2; ++kb) {
        __syncthreads();
        for (int g = tid; g < 2048; g += 256) {
            int row = g >> 4, off = g & 15;
            float4 f = VV4[(size_t)(grow + row) * 32 + kb * 16 + off];
            float4 h = VV4[(size_t)(gcol + row) * 32 + kb * 16 + off];
            int kk = off * 2;
            Ar1[kk * 132 + row] = f.x; Ar2[kk * 132 + row] = f.y;
            Ar1[(kk + 1) * 132 + row] = f.z; Ar2[(kk + 1) * 132 + row] = f.w;
            Ac1[kk * 132 + row] = h.x; Ac2[kk * 132 + row] = h.y;
            Ac1[(kk + 1) * 132 + row] = h.z; Ac2[(kk + 1) * 132 + row] = h.w;
        }
        __syncthreads();
#pragma unroll 2
        for (int k = 0; k < 32; ++k) {
            float rv1[8], rv2[8], cv1[8], cv2[8];
            *(float4*)&rv1[0] = *(const float4*)&Ar1[k * 132 + trow * 4];
            *(float4*)&rv1[4] = *(const float4*)&Ar1[k * 132 + 64 + trow * 4];
            *(float4*)&rv2[0] = *(const float4*)&Ar2[k * 132 + trow * 4];
            *(float4*)&rv2[4] = *(const float4*)&Ar2[k * 132 + 64 + trow * 4];
            *(float4*)&cv1[0] = *(const float4*)&Ac1[k * 132 + tcol * 4];
            *(float4*)&cv1[4] = *(const float4*)&Ac1[k * 132 + 64 + tcol * 4];
            *(float4*)&cv2[0] = *(const float4*)&Ac2[k * 132 + tcol * 4];
            *(float4*)&cv2[4] = *(const float4*)&Ac2[k * 132 + 64 + tcol * 4];
#pragma unroll
            for (int r = 0; r < 8; ++r)
#pragma unroll
                for (int c = 0; c < 8; ++c) {
                    d1[r][c] = fmaf(rv1[r], cv2[c], d1[r][c]);
                    d2[r][c] = fmaf(rv2[r], cv1[c], d2[r][c]);
                }
        }
    }

    // Direct tile: out[grow+r][gcol+c] = relu(d1-d2)
#pragma unroll
    for (int rr = 0; rr < 8; ++rr) {
        int r = (rr < 4) ? (trow * 4 + rr) : (64 + trow * 4 + (rr - 4));
        float4 o0, o1;
        o0.x = fmaxf(d1[rr][0] - d2[rr][0], 0.0f);
        o0.y = fmaxf(d1[rr][1] - d2[rr][1], 0.0f);
        o0.z = fmaxf(d1[rr][2] - d2[rr][2], 0.0f);
        o0.w = fmaxf(d1[rr][3] - d2[rr][3], 0.0f);
        o1.x = fmaxf(d1[rr][4] - d2[rr][4], 0.0f);
        o1.y = fmaxf(d1[rr][5] - d2[rr][5], 0.0f);
        o1.z = fmaxf(d1[rr][6] - d2[rr][6], 0.0f);
        o1.w = fmaxf(d1[rr][7] - d2[rr][7], 0.0f);
        float* op = out + (size_t)(grow + r) * 8192 + gcol;
        *(float4*)(op + tcol * 4)      = o0;
        *(float4*)(op + 64 + tcol * 4) = o1;
    }

    // Mirror tile: out[gcol+c][grow+r] = relu(d2-d1)[r][c], via LDS transpose.
    __syncthreads();                     // all LDS k-reads done; reuse smem
    float (*tT)[132] = (float(*)[132])smem;   // [128][132]
#pragma unroll
    for (int rr = 0; rr < 8; ++rr) {
        int r = (rr < 4) ? (trow * 4 + rr) : (64 + trow * 4 + (rr - 4));
#pragma unroll
        for (int cc = 0; cc < 8; ++cc) {
            int c = (cc < 4) ? (tcol * 4 + cc) : (64 + tcol * 4 + (cc - 4));
            tT[c][r] = fmaxf(d2[rr][cc] - d1[rr][cc], 0.0f);
        }
    }
    __syncthreads();
    for (int g = tid; g < 4096; g += 256) {          // FIX: 4096 float4s
        int orow_ = g >> 5, off = g & 31;            // FIX: 32 float4s/row
        float4 v = *(const float4*)&tT[orow_][off * 4];
        *(float4*)(out + (size_t)(gcol + orow_) * 8192 + grow + off * 4) = v;
    }
}

// ---------------------------------------------------------------------------
// Kernel 3 (v3): per-row top-32 of (adj + noise*0.01), keys in registers.
// One 1024-bin histogram (key bits [31:22]); boundary bin via single-wave
// shfl suffix-scan; collect all keys >= bin floor (<=1024 expected ~150-350);
// exact rank-select (key desc, idx asc — matches lax.top_k). Rare overflow:
// refine 10 bits/level. Then zero row + scatter 32 exact adj values.
// ---------------------------------------------------------------------------
__device__ __forceinline__ unsigned fkey(float f) {
    unsigned u = __float_as_uint(f);
    return (u & 0x80000000u) ? ~u : (u | 0x80000000u);
}

// hist[1024] -> pick bin with (#strictly above) < krem <= (#above + bin count)
__device__ __forceinline__ void select_bin1024(
    const unsigned* __restrict__ hist, unsigned* __restrict__ chs,
    int tid, int krem, int* __restrict__ sh_bin, int* __restrict__ sh_above)
{
    chs[tid] = hist[tid * 4 + 0] + hist[tid * 4 + 1] +
               hist[tid * 4 + 2] + hist[tid * 4 + 3];
    __syncthreads();
    if (tid < 64) {
        unsigned g = chs[tid * 4 + 0] + chs[tid * 4 + 1] +
                     chs[tid * 4 + 2] + chs[tid * 4 + 3];
        unsigned v = g;                        // suffix-inclusive scan (high bins)
#pragma unroll
        for (int off = 1; off < 64; off <<= 1) {
            unsigned o = __shfl_down(v, off);
            if (tid + off < 64) v += o;
        }
        unsigned above = v - g;
        if (above < (unsigned)krem && (unsigned)krem <= above + g) {
            unsigned cum = above;
            int bin = -1;
            for (int c = 3; c >= 0 && bin < 0; --c) {
                unsigned cs = chs[tid * 4 + c];
                if (cum + cs >= (unsigned)krem) {
                    int cb = tid * 4 + c;
                    for (int b = 3; b >= 0; --b) {
                        unsigned h = hist[cb * 4 + b];
                        if (cum + h >= (unsigned)krem) { bin = cb * 4 + b; break; }
                        cum += h;
                    }
                } else cum += cs;
            }
            *sh_bin = bin; *sh_above = (int)cum;
        }
    }
    __syncthreads();
}

#define TK_CAP 1024

__global__ __launch_bounds__(256) void topk_select(
    const float* __restrict__ noise, float* __restrict__ out)
{
    __shared__ unsigned hist[1024];
    __shared__ unsigned chs[256];
    __shared__ unsigned ckey[TK_CAP];
    __shared__ int      cidx[TK_CAP];
    __shared__ int      wlist[32];
    __shared__ float    wval[32];
    __shared__ int      sh_bin, sh_above;
    __shared__ unsigned sh_cnt;

    int tid = threadIdx.x;
    int row = blockIdx.x;
    float*       orow = out   + (size_t)row * 8192;
    const float* nrow = noise + (size_t)row * 8192;
    const float4* o4 = (const float4*)orow;
    const float4* n4 = (const float4*)nrow;

    for (int i = tid; i < 1024; i += 256) hist[i] = 0u;
    __syncthreads();

    unsigned kk[32];                 // register key array (constant indexing)
#pragma unroll
    for (int i = 0; i < 8; ++i) {
        int t = tid + i * 256;
        float4 a  = o4[t];
        float4 nz = n4[t];
        unsigned q0 = fkey(__fadd_rn(a.x, __fmul_rn(nz.x, 0.01f)));
        unsigned q1 = fkey(__fadd_rn(a.y, __fmul_rn(nz.y, 0.01f)));
        unsigned q2 = fkey(__fadd_rn(a.z, __fmul_rn(nz.z, 0.01f)));
        unsigned q3 = fkey(__fadd_rn(a.w, __fmul_rn(nz.w, 0.01f)));
        kk[i * 4 + 0] = q0; kk[i * 4 + 1] = q1;
        kk[i * 4 + 2] = q2; kk[i * 4 + 3] = q3;
        atomicAdd(&hist[q0 >> 22], 1u);
        atomicAdd(&hist[q1 >> 22], 1u);
        atomicAdd(&hist[q2 >> 22], 1u);
        atomicAdd(&hist[q3 >> 22], 1u);
    }
    __syncthreads();

    int shiftv = 22;
    select_bin1024(hist, chs, tid, 32, &sh_bin, &sh_above);
    unsigned Tf = ((unsigned)sh_bin) << 22;
    int cum = sh_above;

    int cnt;
    for (;;) {
        if (tid == 0) sh_cnt = 0u;
        __syncthreads();
#pragma unroll
        for (int i = 0; i < 32; ++i) {
            if (kk[i] >= Tf) {
                unsigned p = atomicAdd(&sh_cnt, 1u);
                if (p < TK_CAP) {
                    ckey[p] = kk[i];
                    cidx[p] = tid * 4 + (i >> 2) * 1024 + (i & 3);
                }
            }
        }
        __syncthreads();
        cnt = (int)sh_cnt;
        if (cnt <= TK_CAP || shiftv <= 2) break;
        // refine 10 more bits within the chosen bin
        int prevShift = shiftv;
        unsigned prevTop = Tf >> prevShift;
        shiftv -= 10;                         // 22 -> 12 -> 2
        for (int i = tid; i < 1024; i += 256) hist[i] = 0u;
        __syncthreads();
#pragma unroll
        for (int i = 0; i < 32; ++i) {
            unsigned k = kk[i];
            if ((k >> prevShift) == prevTop)
                atomicAdd(&hist[(k >> shiftv) & 0x3FFu], 1u);
        }
        __syncthreads();
        select_bin1024(hist, chs, tid, 32 - cum, &sh_bin, &sh_above);
        Tf |= ((unsigned)sh_bin) << shiftv;
        cum += sh_above;
    }
    if (cnt > TK_CAP) cnt = TK_CAP;           // unreachable in practice

    // Exact rank select among candidates (total order: key desc, idx asc).
    for (int t = tid; t < cnt; t += 256) {
        unsigned mk = ckey[t];
        int mi = cidx[t];
        int rank = 0;
        for (int j = 0; j < cnt; ++j) {
            unsigned ok = ckey[j];
            rank += (ok > mk || (ok == mk && cidx[j] < mi)) ? 1 : 0;
        }
        if (rank < 32) wlist[rank] = mi;
    }
    __syncthreads();
    if (tid < 32) wval[tid] = orow[wlist[tid]];   // adj values, pre-overwrite
    __syncthreads();                              // loads drained before zeroing
    float4 z = make_float4(0.0f, 0.0f, 0.0f, 0.0f);
#pragma unroll
    for (int i = 0; i < 8; ++i) ((float4*)orow)[tid + i * 256] = z;
    __syncthreads();
    if (tid < 32) orow[wlist[tid]] = wval[tid];
}

// ---------------------------------------------------------------------------
extern "C" void kernel_launch(void* const* d_in, const int* in_sizes, int n_in,
                              void* d_out, int out_size, void* d_ws, size_t ws_size,
                              hipStream_t stream) {
    (void)in_sizes; (void)n_in; (void)out_size; (void)ws_size;
    const float* emb   = (const float*)d_in[0];
    const float* noise = (const float*)d_in[1];
    const float* W1    = (const float*)d_in[2];
    const float* b1    = (const float*)d_in[3];
    const float* W2    = (const float*)d_in[4];
    const float* b2    = (const float*)d_in[5];
    float* out = (float*)d_out;
    float* VV  = (float*)d_ws;   // 8192*128 floats = 4 MiB scratch

    hipLaunchKernelGGL(compute_vv, dim3(4096), dim3(256), 0, stream,
                       emb, W1, b1, W2, b2, VV);
    hipLaunchKernelGGL(adj_gemm_tri, dim3(64, 64), dim3(256), 0, stream, VV, out);
    hipLaunchKernelGGL(topk_select, dim3(8192), dim3(256), 0, stream, noise, out);
}

// Round 5
// 656.792 us; speedup vs baseline: 2.6079x; 1.0252x over previous
//
#include <hip/hip_runtime.h>
#include <math.h>

// Problem constants: N=8192, DIM=64, K=32, ALPHA=1.0
// d_in order: node_emb[8192*64], noise[8192*8192], W1[64*64], b1[64], W2[64*64], b2[64]
// out: 8192*8192 fp32

// ---------------------------------------------------------------------------
// Kernel 1: VV[i][2k] = v1[i][k], VV[i][2k+1] = v2[i][k]
// v = gelu(emb @ W.T + b), exact-erf gelu. In-order fmaf over k (BLAS-like).
// ---------------------------------------------------------------------------
__global__ __launch_bounds__(256) void compute_vv(
    const float* __restrict__ emb, const float* __restrict__ W1,
    const float* __restrict__ b1, const float* __restrict__ W2,
    const float* __restrict__ b2, float* __restrict__ VV)
{
    __shared__ float sW[2][64 * 65];
    __shared__ float sb[2][64];
    __shared__ float semb[2][64];
    int tid = threadIdx.x;
    for (int t = tid; t < 64 * 64; t += 256) {
        int o = t >> 6, k = t & 63;
        sW[0][o * 65 + k] = W1[t];
        sW[1][o * 65 + k] = W2[t];
    }
    if (tid < 64) { sb[0][tid] = b1[tid]; sb[1][tid] = b2[tid]; }
    int i0 = blockIdx.x * 2;
    if (tid < 128) semb[tid >> 6][tid & 63] = emb[(size_t)i0 * 64 + tid];
    __syncthreads();

    int li = tid >> 7;
    int c  = tid & 127;
    int o  = c >> 1;
    int w  = c & 1;
    const float* wr = &sW[w][o * 65];
    const float* e  = &semb[li][0];
    float acc = 0.0f;
#pragma unroll
    for (int k = 0; k < 64; ++k) acc = fmaf(e[k], wr[k], acc);
    float x = acc + sb[w][o];
    double xd = (double)x;
    double g = 0.5 * xd * (1.0 + erf(xd * 0.70710678118654752440));
    VV[(size_t)(i0 + li) * 128 + c] = (float)g;
}

// ---------------------------------------------------------------------------
// Kernel 2: adj = relu(v1 v2^T - v2 v1^T), antisymmetric (upper-tri compute,
// bit-exact mirror via fmaf commutativity). Unchanged from round 4.
// ---------------------------------------------------------------------------
__global__ __launch_bounds__(256, 2) void adj_gemm_tri(
    const float* __restrict__ VV, float* __restrict__ out)
{
    int bi = blockIdx.x, bj = blockIdx.y;
    if (bj < bi) return;

    __shared__ __align__(16) float smem[16896];
    float* Ar1 = smem;
    float* Ar2 = smem + 4224;
    float* Ac1 = smem + 8448;
    float* Ac2 = smem + 12672;

    int tid  = threadIdx.x;
    int trow = tid >> 4, tcol = tid & 15;
    const int grow = bi * 128, gcol = bj * 128;

    float d1[8][8], d2[8][8];
#pragma unroll
    for (int r = 0; r < 8; ++r)
#pragma unroll
        for (int c = 0; c < 8; ++c) { d1[r][c] = 0.0f; d2[r][c] = 0.0f; }

    const float4* VV4 = (const float4*)VV;
    for (int kb = 0; kb < 2; ++kb) {
        __syncthreads();
        for (int g = tid; g < 2048; g += 256) {
            int row = g >> 4, off = g & 15;
            float4 f = VV4[(size_t)(grow + row) * 32 + kb * 16 + off];
            float4 h = VV4[(size_t)(gcol + row) * 32 + kb * 16 + off];
            int kk = off * 2;
            Ar1[kk * 132 + row] = f.x; Ar2[kk * 132 + row] = f.y;
            Ar1[(kk + 1) * 132 + row] = f.z; Ar2[(kk + 1) * 132 + row] = f.w;
            Ac1[kk * 132 + row] = h.x; Ac2[kk * 132 + row] = h.y;
            Ac1[(kk + 1) * 132 + row] = h.z; Ac2[(kk + 1) * 132 + row] = h.w;
        }
        __syncthreads();
#pragma unroll 2
        for (int k = 0; k < 32; ++k) {
            float rv1[8], rv2[8], cv1[8], cv2[8];
            *(float4*)&rv1[0] = *(const float4*)&Ar1[k * 132 + trow * 4];
            *(float4*)&rv1[4] = *(const float4*)&Ar1[k * 132 + 64 + trow * 4];
            *(float4*)&rv2[0] = *(const float4*)&Ar2[k * 132 + trow * 4];
            *(float4*)&rv2[4] = *(const float4*)&Ar2[k * 132 + 64 + trow * 4];
            *(float4*)&cv1[0] = *(const float4*)&Ac1[k * 132 + tcol * 4];
            *(float4*)&cv1[4] = *(const float4*)&Ac1[k * 132 + 64 + tcol * 4];
            *(float4*)&cv2[0] = *(const float4*)&Ac2[k * 132 + tcol * 4];
            *(float4*)&cv2[4] = *(const float4*)&Ac2[k * 132 + 64 + tcol * 4];
#pragma unroll
            for (int r = 0; r < 8; ++r)
#pragma unroll
                for (int c = 0; c < 8; ++c) {
                    d1[r][c] = fmaf(rv1[r], cv2[c], d1[r][c]);
                    d2[r][c] = fmaf(rv2[r], cv1[c], d2[r][c]);
                }
        }
    }

#pragma unroll
    for (int rr = 0; rr < 8; ++rr) {
        int r = (rr < 4) ? (trow * 4 + rr) : (64 + trow * 4 + (rr - 4));
        float4 o0, o1;
        o0.x = fmaxf(d1[rr][0] - d2[rr][0], 0.0f);
        o0.y = fmaxf(d1[rr][1] - d2[rr][1], 0.0f);
        o0.z = fmaxf(d1[rr][2] - d2[rr][2], 0.0f);
        o0.w = fmaxf(d1[rr][3] - d2[rr][3], 0.0f);
        o1.x = fmaxf(d1[rr][4] - d2[rr][4], 0.0f);
        o1.y = fmaxf(d1[rr][5] - d2[rr][5], 0.0f);
        o1.z = fmaxf(d1[rr][6] - d2[rr][6], 0.0f);
        o1.w = fmaxf(d1[rr][7] - d2[rr][7], 0.0f);
        float* op = out + (size_t)(grow + r) * 8192 + gcol;
        *(float4*)(op + tcol * 4)      = o0;
        *(float4*)(op + 64 + tcol * 4) = o1;
    }

    __syncthreads();
    float (*tT)[132] = (float(*)[132])smem;
#pragma unroll
    for (int rr = 0; rr < 8; ++rr) {
        int r = (rr < 4) ? (trow * 4 + rr) : (64 + trow * 4 + (rr - 4));
#pragma unroll
        for (int cc = 0; cc < 8; ++cc) {
            int c = (cc < 4) ? (tcol * 4 + cc) : (64 + tcol * 4 + (cc - 4));
            tT[c][r] = fmaxf(d2[rr][cc] - d1[rr][cc], 0.0f);
        }
    }
    __syncthreads();
    for (int g = tid; g < 4096; g += 256) {
        int orow_ = g >> 5, off = g & 31;
        float4 v = *(const float4*)&tT[orow_][off * 4];
        *(float4*)(out + (size_t)(gcol + orow_) * 8192 + grow + off * 4) = v;
    }
}

// ---------------------------------------------------------------------------
// Kernel 3 (v4, linear-bin select): per-row top-32 of (adj + noise*0.01).
// Scores >= 0. Linear bins bin=floor(score*128) spread positive-adj scores
// over ~1000 bins (near-conflict-free LDS atomics, unlike fp-key radix where
// exponent clustering serialized ~6-way). Entries with score < 2^-6 are
// skipped (cannot reach top-32; exact fallback if row has <32 above). Exact
// floor-binning via dyadic-boundary compares keeps selection == lax.top_k.
// Scores + adj values live in registers; final write is one flags-masked
// register pass (no winner re-read, no zero+scatter).
// ---------------------------------------------------------------------------
#define SKIPV 0.015625f   // 2^-6
#define CAP   1024

// Exact floor bin: b such that lo + b*inv <= s < lo + (b+1)*inv, clamped 1023.
// lo, inv dyadic => compares exact; fixes fp rounding in (s-lo)*scale.
__device__ __forceinline__ int binof(float s, float lo, float scale, float inv) {
    int b = (int)((s - lo) * scale);
    if (b > 1023) b = 1023;
    if (lo + (float)b * inv > s) --b;                       // rounded up
    else if (b < 1023 && lo + (float)(b + 1) * inv <= s) ++b; // rounded down
    return b;
}

// hist[1024] -> bin where cumulative-from-top crosses krem.
// sh_above = #elements strictly above chosen bin; sh_total = sum(hist).
__device__ __forceinline__ void select_bin1024(
    const unsigned* __restrict__ hist, unsigned* __restrict__ chs,
    int tid, int krem, int* __restrict__ sh_bin, int* __restrict__ sh_above,
    unsigned* __restrict__ sh_total)
{
    chs[tid] = hist[tid * 4 + 0] + hist[tid * 4 + 1] +
               hist[tid * 4 + 2] + hist[tid * 4 + 3];
    __syncthreads();
    if (tid < 64) {
        unsigned g = chs[tid * 4 + 0] + chs[tid * 4 + 1] +
                     chs[tid * 4 + 2] + chs[tid * 4 + 3];
        unsigned v = g;
#pragma unroll
        for (int off = 1; off < 64; off <<= 1) {
            unsigned o = __shfl_down(v, off);
            if (tid + off < 64) v += o;
        }
        if (tid == 0) *sh_total = v;
        unsigned above = v - g;
        if (above < (unsigned)krem && (unsigned)krem <= above + g) {
            unsigned cum = above;
            int bin = -1;
            for (int c = 3; c >= 0 && bin < 0; --c) {
                unsigned cs = chs[tid * 4 + c];
                if (cum + cs >= (unsigned)krem) {
                    int cb = tid * 4 + c;
                    for (int b = 3; b >= 0; --b) {
                        unsigned h = hist[cb * 4 + b];
                        if (cum + h >= (unsigned)krem) { bin = cb * 4 + b; break; }
                        cum += h;
                    }
                } else cum += cs;
            }
            *sh_bin = bin; *sh_above = (int)cum;
        }
    }
    __syncthreads();
}

__global__ __launch_bounds__(256) void topk_linear(
    const float* __restrict__ noise, float* __restrict__ out)
{
    __shared__ unsigned hist[1024];
    __shared__ unsigned chs[256];
    __shared__ float    cs[CAP];
    __shared__ int      ci[CAP];
    __shared__ unsigned flags[256];
    __shared__ int      sh_bin, sh_above;
    __shared__ unsigned sh_total, sh_cnt;

    int tid = threadIdx.x;
    int row = blockIdx.x;
    float*       orow = out   + (size_t)row * 8192;
    const float* nrow = noise + (size_t)row * 8192;
    const float4* o4 = (const float4*)orow;
    const float4* n4 = (const float4*)nrow;

    // Issue all global loads first (overlaps LDS init), scores as ref:
    // __fadd_rn(adj, __fmul_rn(noise, 0.01f)) — no FMA contraction.
    float ss[32], aa[32];
#pragma unroll
    for (int i = 0; i < 8; ++i) {
        float4 a  = o4[tid + i * 256];
        float4 nz = n4[tid + i * 256];
        aa[i * 4 + 0] = a.x; ss[i * 4 + 0] = __fadd_rn(a.x, __fmul_rn(nz.x, 0.01f));
        aa[i * 4 + 1] = a.y; ss[i * 4 + 1] = __fadd_rn(a.y, __fmul_rn(nz.y, 0.01f));
        aa[i * 4 + 2] = a.z; ss[i * 4 + 2] = __fadd_rn(a.z, __fmul_rn(nz.z, 0.01f));
        aa[i * 4 + 3] = a.w; ss[i * 4 + 3] = __fadd_rn(a.w, __fmul_rn(nz.w, 0.01f));
    }
    for (int i = tid; i < 1024; i += 256) hist[i] = 0u;
    flags[tid] = 0u;
    __syncthreads();

    // Level-0 histogram: only scores >= 2^-6, bin = floor(s*128).
#pragma unroll
    for (int s = 0; s < 32; ++s) {
        if (ss[s] >= SKIPV)
            atomicAdd(&hist[binof(ss[s], 0.0f, 128.0f, 0.0078125f)], 1u);
    }
    __syncthreads();

    select_bin1024(hist, chs, tid, 32, &sh_bin, &sh_above, &sh_total);
    float Tf, lo, width;
    int krem;
    if (sh_total >= 32u) {                       // normal path (always, in practice)
        Tf    = (float)sh_bin * 0.0078125f;
        krem  = 32 - sh_above;
        lo    = Tf; width = 0.0078125f;
    } else {
        // Rare exact fallback: top-32 dips below 2^-6. All remaining scores
        // are < 2^-6; spread them over 1024 bins of width 2^-16.
        int kr2 = 32 - (int)sh_total;
        __syncthreads();
        for (int i = tid; i < 1024; i += 256) hist[i] = 0u;
        __syncthreads();
#pragma unroll
        for (int s = 0; s < 32; ++s) {
            if (ss[s] < SKIPV)
                atomicAdd(&hist[binof(ss[s], 0.0f, 65536.0f, 1.525878906e-5f)], 1u);
        }
        __syncthreads();
        select_bin1024(hist, chs, tid, kr2, &sh_bin, &sh_above, &sh_total);
        Tf    = (float)sh_bin * 1.525878906e-5f;
        krem  = kr2 - sh_above;
        lo    = Tf; width = 1.525878906e-5f;
    }

    // Collect candidates (s >= Tf), refining if > CAP (practically never).
    int cnt;
    for (int pass = 0;; ++pass) {
        if (tid == 0) sh_cnt = 0u;
        __syncthreads();
#pragma unroll
        for (int s = 0; s < 32; ++s) {
            if (ss[s] >= Tf) {
                unsigned p = atomicAdd(&sh_cnt, 1u);
                if (p < CAP) {
                    cs[p] = ss[s];
                    ci[p] = tid * 4 + (s >> 2) * 1024 + (s & 3);
                }
            }
        }
        __syncthreads();
        cnt = (int)sh_cnt;
        if (cnt <= CAP || pass >= 2) break;
        // refine within [lo, lo+width): 1024 sub-bins
        for (int i = tid; i < 1024; i += 256) hist[i] = 0u;
        __syncthreads();
        float scale = 1024.0f / width;
        float inv   = width * 0.0009765625f;     // width/1024, dyadic
#pragma unroll
        for (int s = 0; s < 32; ++s) {
            if (ss[s] >= lo && ss[s] < lo + width)
                atomicAdd(&hist[binof(ss[s], lo, scale, inv)], 1u);
        }
        __syncthreads();
        select_bin1024(hist, chs, tid, krem, &sh_bin, &sh_above, &sh_total);
        Tf    = lo + (float)sh_bin * inv;
        krem -= sh_above;
        lo    = Tf; width = inv;
    }
    if (cnt > CAP) cnt = CAP;                    // unreachable with continuous noise

    // Exact rank select (score desc, idx asc == lax.top_k); winners -> flags.
    for (int t = tid; t < cnt; t += 256) {
        float msv = cs[t];
        int   mi  = ci[t];
        int rank = 0;
        for (int j = 0; j < cnt; ++j) {
            float os = cs[j];
            rank += (os > msv || (os == msv && ci[j] < mi)) ? 1 : 0;
        }
        if (rank < 32) atomicOr(&flags[mi >> 5], 1u << (mi & 31));
    }
    __syncthreads();

    // Masked writeback from registers: adj where selected, else 0.
#pragma unroll
    for (int i = 0; i < 8; ++i) {
        int j0 = 4 * (tid + i * 256);
        unsigned w = flags[j0 >> 5];
        int sh = j0 & 31;                        // j0 % 32, multiple of 4
        float4 o;
        o.x = ((w >> (sh + 0)) & 1u) ? aa[i * 4 + 0] : 0.0f;
        o.y = ((w >> (sh + 1)) & 1u) ? aa[i * 4 + 1] : 0.0f;
        o.z = ((w >> (sh + 2)) & 1u) ? aa[i * 4 + 2] : 0.0f;
        o.w = ((w >> (sh + 3)) & 1u) ? aa[i * 4 + 3] : 0.0f;
        ((float4*)orow)[tid + i * 256] = o;
    }
}

// ---------------------------------------------------------------------------
extern "C" void kernel_launch(void* const* d_in, const int* in_sizes, int n_in,
                              void* d_out, int out_size, void* d_ws, size_t ws_size,
                              hipStream_t stream) {
    (void)in_sizes; (void)n_in; (void)out_size; (void)ws_size;
    const float* emb   = (const float*)d_in[0];
    const float* noise = (const float*)d_in[1];
    const float* W1    = (const float*)d_in[2];
    const float* b1    = (const float*)d_in[3];
    const float* W2    = (const float*)d_in[4];
    const float* b2    = (const float*)d_in[5];
    float* out = (float*)d_out;
    float* VV  = (float*)d_ws;   // 8192*128 floats = 4 MiB scratch

    hipLaunchKernelGGL(compute_vv, dim3(4096), dim3(256), 0, stream,
                       emb, W1, b1, W2, b2, VV);
    hipLaunchKernelGGL(adj_gemm_tri, dim3(64, 64), dim3(256), 0, stream, VV, out);
    hipLaunchKernelGGL(topk_linear, dim3(8192), dim3(256), 0, stream, noise, out);
}